// Round 2
// baseline (607.162 us; speedup 1.0000x reference)
//
#include <hip/hip_runtime.h>
#include <hip/hip_bf16.h>

#define N_IN_DIM 128
#define N_HID 256

// ---------------------------------------------------------------------------
// CSR build: histogram -> chunk scan -> partial scan -> add offsets -> fill
// ---------------------------------------------------------------------------
__global__ void k_hist(const int* __restrict__ dst, int* __restrict__ deg, int nE) {
  int i = blockIdx.x * blockDim.x + threadIdx.x;
  if (i < nE) atomicAdd(&deg[dst[i]], 1);
}

// nchunk blocks x 256 threads, 4 items/thread: exclusive scan within 1024-chunk,
// chunk total to partials[].
__global__ void k_scan_chunks(const int* __restrict__ deg, int* __restrict__ excl,
                              int* __restrict__ partials, int n) {
  __shared__ int sd[256];
  const int t = threadIdx.x;
  const int base = blockIdx.x * 1024 + t * 4;
  int v0 = (base + 0 < n) ? deg[base + 0] : 0;
  int v1 = (base + 1 < n) ? deg[base + 1] : 0;
  int v2 = (base + 2 < n) ? deg[base + 2] : 0;
  int v3 = (base + 3 < n) ? deg[base + 3] : 0;
  sd[t] = v0 + v1 + v2 + v3;
  __syncthreads();
  for (int off = 1; off < 256; off <<= 1) {
    int x = 0;
    if (t >= off) x = sd[t - off];
    __syncthreads();
    sd[t] += x;
    __syncthreads();
  }
  int run = (t > 0) ? sd[t - 1] : 0;
  if (base + 0 < n) excl[base + 0] = run;
  run += v0;
  if (base + 1 < n) excl[base + 1] = run;
  run += v1;
  if (base + 2 < n) excl[base + 2] = run;
  run += v2;
  if (base + 3 < n) excl[base + 3] = run;
  if (t == 255) partials[blockIdx.x] = sd[255];
}

// single wave: exclusive scan of chunk partials (nchunk <= 64)
__global__ void k_scan_partials(int* __restrict__ partials, int nchunk) {
  const int t = threadIdx.x;
  int orig = (t < nchunk) ? partials[t] : 0;
  int v = orig;
  for (int off = 1; off < 64; off <<= 1) {
    int y = __shfl_up(v, off, 64);
    if (t >= off) v += y;
  }
  if (t < nchunk) partials[t] = v - orig;  // exclusive
}

__global__ void k_add_offsets(int* __restrict__ rowstart, const int* __restrict__ chunk_off,
                              int n, int nE) {
  int i = blockIdx.x * blockDim.x + threadIdx.x;
  if (i < n) rowstart[i] += chunk_off[i >> 10];
  if (i == n) rowstart[n] = nE;
}

__global__ void k_fill(const int* __restrict__ src, const int* __restrict__ dst,
                       const int* __restrict__ rowstart, int* __restrict__ cursor,
                       int* __restrict__ csr, int nE) {
  int i = blockIdx.x * blockDim.x + threadIdx.x;
  if (i < nE) {
    int d = dst[i];
    int p = rowstart[d] + atomicAdd(&cursor[d], 1);
    csr[p] = src[i];
  }
}

// ---------------------------------------------------------------------------
// Mean aggregation: one wave per node, register accumulation, 2x unrolled to
// overlap the dependent csr->row load chains.
// ---------------------------------------------------------------------------
__global__ void k_agg128(const float* __restrict__ X, const int* __restrict__ rs,
                         const int* __restrict__ csr, float* __restrict__ outv, int M) {
  int wid = (blockIdx.x * blockDim.x + threadIdx.x) >> 6;
  int lane = threadIdx.x & 63;
  if (wid >= M) return;
  int s0 = rs[wid], s1 = rs[wid + 1];
  float2 acc = make_float2(0.f, 0.f);
  int e = s0;
  for (; e + 1 < s1; e += 2) {
    int sa = csr[e], sb = csr[e + 1];
    float2 va = *(const float2*)&X[(size_t)sa * 128 + lane * 2];
    float2 vb = *(const float2*)&X[(size_t)sb * 128 + lane * 2];
    acc.x += va.x + vb.x;
    acc.y += va.y + vb.y;
  }
  if (e < s1) {
    int sa = csr[e];
    float2 va = *(const float2*)&X[(size_t)sa * 128 + lane * 2];
    acc.x += va.x;
    acc.y += va.y;
  }
  float inv = 1.0f / fmaxf((float)(s1 - s0), 1.0f);
  *(float2*)&outv[(size_t)wid * 128 + lane * 2] = make_float2(acc.x * inv, acc.y * inv);
}

__global__ void k_agg256(const float* __restrict__ X, const int* __restrict__ rs,
                         const int* __restrict__ csr, float* __restrict__ outv, int M) {
  int wid = (blockIdx.x * blockDim.x + threadIdx.x) >> 6;
  int lane = threadIdx.x & 63;
  if (wid >= M) return;
  int s0 = rs[wid], s1 = rs[wid + 1];
  float4 acc = make_float4(0.f, 0.f, 0.f, 0.f);
  int e = s0;
  for (; e + 1 < s1; e += 2) {
    int sa = csr[e], sb = csr[e + 1];
    float4 va = *(const float4*)&X[(size_t)sa * 256 + lane * 4];
    float4 vb = *(const float4*)&X[(size_t)sb * 256 + lane * 4];
    acc.x += va.x + vb.x;
    acc.y += va.y + vb.y;
    acc.z += va.z + vb.z;
    acc.w += va.w + vb.w;
  }
  if (e < s1) {
    int sa = csr[e];
    float4 va = *(const float4*)&X[(size_t)sa * 256 + lane * 4];
    acc.x += va.x;
    acc.y += va.y;
    acc.z += va.z;
    acc.w += va.w;
  }
  float inv = 1.0f / fmaxf((float)(s1 - s0), 1.0f);
  float4 o = make_float4(acc.x * inv, acc.y * inv, acc.z * inv, acc.w * inv);
  *(float4*)&outv[(size_t)wid * 256 + lane * 4] = o;
}

// ---------------------------------------------------------------------------
// Dual SGEMM: C[M][256] = act(A1[M][K]@W1[K][256] + A2[M][K]@W2[K][256] + bias)
// BM=64, BN=256 (full), BK=16; 256 threads; 8x8 thread tile.
// ---------------------------------------------------------------------------
__global__ __launch_bounds__(256) void k_gemm_dual(
    const float* __restrict__ A1, const float* __restrict__ W1,
    const float* __restrict__ A2, const float* __restrict__ W2,
    const float* __restrict__ bias, float* __restrict__ C,
    int M, int K, int do_relu) {
  __shared__ float As[16][68];   // [k][m], padded: row stride 272B (16B-aligned)
  __shared__ float Bs[16][264];  // [k][n], padded: row stride 1056B (16B-aligned)

  const int t = threadIdx.x;
  const int tx = t & 31;  // col group: cols {tx*4..+3} and {128+tx*4..+3}
  const int ty = t >> 5;  // row group 0..7: rows ty*8..ty*8+7
  const int bm0 = blockIdx.x * 64;

  float acc[8][8];
#pragma unroll
  for (int r = 0; r < 8; r++)
#pragma unroll
    for (int c = 0; c < 8; c++) acc[r][c] = 0.f;

  const int arow = t >> 2;       // 0..63
  const int akq = (t & 3) * 4;   // 0,4,8,12
  const int bk = t >> 4;         // 0..15
  const int bc4 = (t & 15) * 4;  // 0..60

  for (int phase = 0; phase < 2; ++phase) {
    const float* __restrict__ A = phase ? A2 : A1;
    const float* __restrict__ W = phase ? W2 : W1;
    for (int k0 = 0; k0 < K; k0 += 16) {
      __syncthreads();
      // stage A tile (64 rows x 16 k), transposed into As[k][m]
      {
        int gr = bm0 + arow;
        float4 v = make_float4(0.f, 0.f, 0.f, 0.f);
        if (gr < M) v = *(const float4*)&A[(size_t)gr * K + k0 + akq];
        As[akq + 0][arow] = v.x;
        As[akq + 1][arow] = v.y;
        As[akq + 2][arow] = v.z;
        As[akq + 3][arow] = v.w;
      }
      // stage B tile (16 k x 256 n), 4x float4 per thread, coalesced rows
      {
        const float* __restrict__ Wr = &W[(size_t)(k0 + bk) * 256];
#pragma unroll
        for (int q = 0; q < 4; q++) {
          *(float4*)&Bs[bk][bc4 + q * 64] = *(const float4*)&Wr[bc4 + q * 64];
        }
      }
      __syncthreads();
#pragma unroll
      for (int kk = 0; kk < 16; kk++) {
        float4 a0 = *(const float4*)&As[kk][ty * 8];
        float4 a1 = *(const float4*)&As[kk][ty * 8 + 4];
        float4 b0 = *(const float4*)&Bs[kk][tx * 4];
        float4 b1 = *(const float4*)&Bs[kk][128 + tx * 4];
        float ar[8] = {a0.x, a0.y, a0.z, a0.w, a1.x, a1.y, a1.z, a1.w};
        float br[8] = {b0.x, b0.y, b0.z, b0.w, b1.x, b1.y, b1.z, b1.w};
#pragma unroll
        for (int r = 0; r < 8; r++)
#pragma unroll
          for (int c = 0; c < 8; c++) acc[r][c] += ar[r] * br[c];
      }
    }
  }

  // epilogue: bias + relu + store
  float4 bias0 = *(const float4*)&bias[tx * 4];
  float4 bias1 = *(const float4*)&bias[128 + tx * 4];
  float bb[8] = {bias0.x, bias0.y, bias0.z, bias0.w, bias1.x, bias1.y, bias1.z, bias1.w};
#pragma unroll
  for (int r = 0; r < 8; r++) {
    int gr = bm0 + ty * 8 + r;
    if (gr >= M) continue;
    float o[8];
#pragma unroll
    for (int c = 0; c < 8; c++) {
      float v = acc[r][c] + bb[c];
      o[c] = do_relu ? fmaxf(v, 0.f) : v;
    }
    *(float4*)&C[(size_t)gr * 256 + tx * 4] = make_float4(o[0], o[1], o[2], o[3]);
    *(float4*)&C[(size_t)gr * 256 + 128 + tx * 4] = make_float4(o[4], o[5], o[6], o[7]);
  }
}

// ---------------------------------------------------------------------------
// Classifier: out[M][16] = h2[M][256] @ wc[256][16] + bc
// ---------------------------------------------------------------------------
__global__ void k_classifier(const float* __restrict__ h2, const float* __restrict__ wc,
                             const float* __restrict__ bc, float* __restrict__ outv, int M) {
  __shared__ float wcs[4096];
  __shared__ float bcs[16];
  const int t = threadIdx.x;
  for (int i = t; i < 4096; i += 256) wcs[i] = wc[i];
  if (t < 16) bcs[t] = bc[t];
  __syncthreads();
  int row = blockIdx.x * 16 + (t >> 4);
  int cls = t & 15;
  if (row >= M) return;
  const float* hr = h2 + (size_t)row * 256;
  float acc = 0.f;
  for (int k = 0; k < 256; k += 4) {
    float4 h = *(const float4*)&hr[k];
    acc += h.x * wcs[(k + 0) * 16 + cls];
    acc += h.y * wcs[(k + 1) * 16 + cls];
    acc += h.z * wcs[(k + 2) * 16 + cls];
    acc += h.w * wcs[(k + 3) * 16 + cls];
  }
  outv[(size_t)row * 16 + cls] = acc + bcs[cls];
}

// ---------------------------------------------------------------------------
extern "C" void kernel_launch(void* const* d_in, const int* in_sizes, int n_in,
                              void* d_out, int out_size, void* d_ws, size_t ws_size,
                              hipStream_t stream) {
  const float* x = (const float*)d_in[0];
  const int* ei = (const int*)d_in[1];
  const float* w1l = (const float*)d_in[2];
  const float* b1l = (const float*)d_in[3];
  const float* w1r = (const float*)d_in[4];
  const float* w2l = (const float*)d_in[5];
  const float* b2l = (const float*)d_in[6];
  const float* w2r = (const float*)d_in[7];
  const float* wc = (const float*)d_in[8];
  const float* bc = (const float*)d_in[9];
  float* outp = (float*)d_out;

  const int nE = in_sizes[1] / 2;           // 600000
  const int M = in_sizes[0] / N_IN_DIM;     // 50000
  const int* src = ei;
  const int* dst = ei + nE;

  char* ws = (char*)d_ws;
  int* deg = (int*)(ws + 0);                  // 200 KB
  int* cursor = (int*)(ws + (size_t)262144);  // 200 KB
  int* rowstart = (int*)(ws + (size_t)524288);
  int* partials = (int*)(ws + (size_t)786432);
  int* csr = (int*)(ws + (size_t)1048576);                // 2.4 MB
  float* neigh1 = (float*)(ws + (size_t)4 * 1024 * 1024); // 25.6 MB (bufA)
  float* h2 = (float*)(ws + (size_t)4 * 1024 * 1024);     // reuses bufA (51.2 MB)
  float* h1 = (float*)(ws + (size_t)56 * 1024 * 1024);    // 51.2 MB
  float* neigh2 = (float*)(ws + (size_t)108 * 1024 * 1024);  // 51.2 MB

  hipMemsetAsync(deg, 0, (size_t)M * sizeof(int), stream);
  hipMemsetAsync(cursor, 0, (size_t)M * sizeof(int), stream);

  const int eb = (nE + 255) / 256;
  k_hist<<<eb, 256, 0, stream>>>(dst, deg, nE);

  const int nchunk = (M + 1023) / 1024;
  k_scan_chunks<<<nchunk, 256, 0, stream>>>(deg, rowstart, partials, M);
  k_scan_partials<<<1, 64, 0, stream>>>(partials, nchunk);
  k_add_offsets<<<(M + 1 + 255) / 256, 256, 0, stream>>>(rowstart, partials, M, nE);
  k_fill<<<eb, 256, 0, stream>>>(src, dst, rowstart, cursor, csr, nE);

  // Layer 1: aggregate x (128) -> neigh1; h1 = relu(neigh1@w1l + b1l + x@w1r)
  k_agg128<<<(M * 64 + 255) / 256, 256, 0, stream>>>(x, rowstart, csr, neigh1, M);
  k_gemm_dual<<<(M + 63) / 64, 256, 0, stream>>>(neigh1, w1l, x, w1r, b1l, h1, M, 128, 1);

  // Layer 2: aggregate h1 (256) -> neigh2; h2 = relu(neigh2@w2l + b2l + h1@w2r)
  k_agg256<<<(M * 64 + 255) / 256, 256, 0, stream>>>(h1, rowstart, csr, neigh2, M);
  k_gemm_dual<<<(M + 63) / 64, 256, 0, stream>>>(neigh2, w2l, h1, w2r, b2l, h2, M, 256, 1);

  // Classifier
  k_classifier<<<(M + 15) / 16, 256, 0, stream>>>(h2, wc, bc, outp, M);
}

// Round 3
// 574.605 us; speedup vs baseline: 1.0567x; 1.0567x over previous
//
#include <hip/hip_runtime.h>
#include <hip/hip_bf16.h>

typedef unsigned short u16;
typedef __attribute__((ext_vector_type(8))) short s16x8;
typedef __attribute__((ext_vector_type(4))) float f32x4;

#define GLOAD16(src, dst)                                                   \
  __builtin_amdgcn_global_load_lds(                                         \
      (const __attribute__((address_space(1))) void*)(src),                 \
      (__attribute__((address_space(3))) void*)(dst), 16, 0, 0)

__device__ inline u16 f2bf(float f) {
  unsigned u = __float_as_uint(f);
  unsigned r = u + 0x7FFFu + ((u >> 16) & 1u);
  return (u16)(r >> 16);
}
__device__ inline float bf2f(u16 h) { return __uint_as_float(((unsigned)h) << 16); }
__device__ inline void split_hl(float f, u16& hi, u16& lo) {
  hi = f2bf(f);
  lo = f2bf(f - bf2f(hi));
}

// ---------------------------------------------------------------------------
// CSR build
// ---------------------------------------------------------------------------
__global__ void k_hist(const int* __restrict__ dst, int* __restrict__ deg, int nE) {
  int i = blockIdx.x * blockDim.x + threadIdx.x;
  if (i < nE) atomicAdd(&deg[dst[i]], 1);
}

__global__ void k_scan_chunks(const int* __restrict__ deg, int* __restrict__ excl,
                              int* __restrict__ partials, int n) {
  __shared__ int sd[256];
  const int t = threadIdx.x;
  const int base = blockIdx.x * 1024 + t * 4;
  int v0 = (base + 0 < n) ? deg[base + 0] : 0;
  int v1 = (base + 1 < n) ? deg[base + 1] : 0;
  int v2 = (base + 2 < n) ? deg[base + 2] : 0;
  int v3 = (base + 3 < n) ? deg[base + 3] : 0;
  sd[t] = v0 + v1 + v2 + v3;
  __syncthreads();
  for (int off = 1; off < 256; off <<= 1) {
    int x = 0;
    if (t >= off) x = sd[t - off];
    __syncthreads();
    sd[t] += x;
    __syncthreads();
  }
  int run = (t > 0) ? sd[t - 1] : 0;
  if (base + 0 < n) excl[base + 0] = run;
  run += v0;
  if (base + 1 < n) excl[base + 1] = run;
  run += v1;
  if (base + 2 < n) excl[base + 2] = run;
  run += v2;
  if (base + 3 < n) excl[base + 3] = run;
  if (t == 255) partials[blockIdx.x] = sd[255];
}

__global__ void k_scan_partials(int* __restrict__ partials, int nchunk) {
  const int t = threadIdx.x;
  int orig = (t < nchunk) ? partials[t] : 0;
  int v = orig;
  for (int off = 1; off < 64; off <<= 1) {
    int y = __shfl_up(v, off, 64);
    if (t >= off) v += y;
  }
  if (t < nchunk) partials[t] = v - orig;
}

__global__ void k_add_offsets(int* __restrict__ rowstart, const int* __restrict__ chunk_off,
                              int n, int nE) {
  int i = blockIdx.x * blockDim.x + threadIdx.x;
  if (i < n) rowstart[i] += chunk_off[i >> 10];
  if (i == n) rowstart[n] = nE;
}

__global__ void k_fill(const int* __restrict__ src, const int* __restrict__ dst,
                       const int* __restrict__ rowstart, int* __restrict__ cursor,
                       int* __restrict__ csr, int nE) {
  int i = blockIdx.x * blockDim.x + threadIdx.x;
  if (i < nE) {
    int d = dst[i];
    int p = rowstart[d] + atomicAdd(&cursor[d], 1);
    csr[p] = src[i];
  }
}

// ---------------------------------------------------------------------------
// fp32 -> bf16 hi/lo plane converters
// ---------------------------------------------------------------------------
__global__ void k_cvt(const float* __restrict__ X, u16* __restrict__ hi,
                      u16* __restrict__ lo, long n) {
  long i = (long)(blockIdx.x * blockDim.x + threadIdx.x) * 4;
  if (i >= n) return;
  float4 v = *(const float4*)&X[i];
  u16 h0, l0, h1, l1, h2, l2, h3, l3;
  split_hl(v.x, h0, l0);
  split_hl(v.y, h1, l1);
  split_hl(v.z, h2, l2);
  split_hl(v.w, h3, l3);
  *(ushort4*)&hi[i] = make_ushort4(h0, h1, h2, h3);
  *(ushort4*)&lo[i] = make_ushort4(l0, l1, l2, l3);
}

// W[K][N] -> WT_hi/lo[N][K]
__global__ void k_cvt_wt(const float* __restrict__ W, u16* __restrict__ thi,
                         u16* __restrict__ tlo, int K, int N) {
  int i = blockIdx.x * blockDim.x + threadIdx.x;
  if (i >= K * N) return;
  int k = i / N, n = i - k * N;
  u16 h, l;
  split_hl(W[i], h, l);
  thi[n * K + k] = h;
  tlo[n * K + k] = l;
}

// ---------------------------------------------------------------------------
// Mean aggregation (one wave per node), hi/lo bf16 outputs
// ---------------------------------------------------------------------------
__global__ void k_agg128_hl(const float* __restrict__ X, const int* __restrict__ rs,
                            const int* __restrict__ csr, u16* __restrict__ ohi,
                            u16* __restrict__ olo, int M) {
  int wid = (blockIdx.x * blockDim.x + threadIdx.x) >> 6;
  int lane = threadIdx.x & 63;
  if (wid >= M) return;
  int s0 = rs[wid], s1 = rs[wid + 1];
  float ax = 0.f, ay = 0.f;
  int e = s0;
  for (; e + 1 < s1; e += 2) {
    int sa = csr[e], sb = csr[e + 1];
    float2 va = *(const float2*)&X[(size_t)sa * 128 + lane * 2];
    float2 vb = *(const float2*)&X[(size_t)sb * 128 + lane * 2];
    ax += va.x + vb.x;
    ay += va.y + vb.y;
  }
  if (e < s1) {
    float2 va = *(const float2*)&X[(size_t)csr[e] * 128 + lane * 2];
    ax += va.x;
    ay += va.y;
  }
  float inv = 1.0f / fmaxf((float)(s1 - s0), 1.0f);
  ax *= inv;
  ay *= inv;
  u16 h0, l0, h1, l1;
  split_hl(ax, h0, l0);
  split_hl(ay, h1, l1);
  size_t o = (size_t)wid * 128 + lane * 2;
  *(ushort2*)&ohi[o] = make_ushort2(h0, h1);
  *(ushort2*)&olo[o] = make_ushort2(l0, l1);
}

__global__ void k_agg256_hl(const u16* __restrict__ Xhi, const u16* __restrict__ Xlo,
                            const int* __restrict__ rs, const int* __restrict__ csr,
                            u16* __restrict__ ohi, u16* __restrict__ olo, int M) {
  int wid = (blockIdx.x * blockDim.x + threadIdx.x) >> 6;
  int lane = threadIdx.x & 63;
  if (wid >= M) return;
  int s0 = rs[wid], s1 = rs[wid + 1];
  float a0 = 0.f, a1 = 0.f, a2 = 0.f, a3 = 0.f;
  int e = s0;
  for (; e + 1 < s1; e += 2) {
    size_t ba = (size_t)csr[e] * 256 + lane * 4;
    size_t bb = (size_t)csr[e + 1] * 256 + lane * 4;
    ushort4 ha = *(const ushort4*)&Xhi[ba];
    ushort4 la = *(const ushort4*)&Xlo[ba];
    ushort4 hb = *(const ushort4*)&Xhi[bb];
    ushort4 lb = *(const ushort4*)&Xlo[bb];
    a0 += bf2f(ha.x) + bf2f(la.x) + bf2f(hb.x) + bf2f(lb.x);
    a1 += bf2f(ha.y) + bf2f(la.y) + bf2f(hb.y) + bf2f(lb.y);
    a2 += bf2f(ha.z) + bf2f(la.z) + bf2f(hb.z) + bf2f(lb.z);
    a3 += bf2f(ha.w) + bf2f(la.w) + bf2f(hb.w) + bf2f(lb.w);
  }
  if (e < s1) {
    size_t ba = (size_t)csr[e] * 256 + lane * 4;
    ushort4 ha = *(const ushort4*)&Xhi[ba];
    ushort4 la = *(const ushort4*)&Xlo[ba];
    a0 += bf2f(ha.x) + bf2f(la.x);
    a1 += bf2f(ha.y) + bf2f(la.y);
    a2 += bf2f(ha.z) + bf2f(la.z);
    a3 += bf2f(ha.w) + bf2f(la.w);
  }
  float inv = 1.0f / fmaxf((float)(s1 - s0), 1.0f);
  a0 *= inv;
  a1 *= inv;
  a2 *= inv;
  a3 *= inv;
  u16 h0, l0, h1, l1, h2, l2, h3, l3;
  split_hl(a0, h0, l0);
  split_hl(a1, h1, l1);
  split_hl(a2, h2, l2);
  split_hl(a3, h3, l3);
  size_t o = (size_t)wid * 256 + lane * 4;
  *(ushort4*)&ohi[o] = make_ushort4(h0, h1, h2, h3);
  *(ushort4*)&olo[o] = make_ushort4(l0, l1, l2, l3);
}

// ---------------------------------------------------------------------------
// Dual bf16x3 MFMA GEMM: C[M][256] = relu(A1@W1 + A2@W2 + bias)
// A*: bf16 hi/lo planes [Mpad][K] row-major. W*: bf16 hi/lo planes [256][K]
// (pre-transposed). BM=64, BN=256, BK=32, 256 thr = 4 waves (wave w owns
// cols [64w,64w+64)). 16x16x32 MFMA, 3 products (hh, lh, hl) per frag pair.
// ---------------------------------------------------------------------------
template <int OUT_HL>
__global__ __launch_bounds__(256) void k_gemm_mfma(
    const u16* __restrict__ A1h, const u16* __restrict__ A1l,
    const u16* __restrict__ A2h, const u16* __restrict__ A2l,
    const u16* __restrict__ W1h, const u16* __restrict__ W1l,
    const u16* __restrict__ W2h, const u16* __restrict__ W2l,
    const float* __restrict__ bias, u16* __restrict__ Ohi, u16* __restrict__ Olo,
    float* __restrict__ Of32, int M, int K) {
  // LDS: A tiles [4 kgrp][64 row][8 k] bf16; B tiles [4 kgrp][256 col][8 k]
  __shared__ short sAh[2048], sAl[2048], sBh[8192], sBl[8192];
  const int t = threadIdx.x;
  const int l = t & 63;
  const int w = t >> 6;
  const int bm0 = blockIdx.x * 64;

  f32x4 acc[4][4];
#pragma unroll
  for (int m = 0; m < 4; m++)
#pragma unroll
    for (int n = 0; n < 4; n++) acc[m][n] = (f32x4){0.f, 0.f, 0.f, 0.f};

  const int srow = t & 63;  // A-stage: dest t*16B == (t>>6)*1024 + (t&63)*16
  const int sg = t >> 6;

  for (int phase = 0; phase < 2; ++phase) {
    const u16* __restrict__ Ah = phase ? A2h : A1h;
    const u16* __restrict__ Al = phase ? A2l : A1l;
    const u16* __restrict__ Wh = phase ? W2h : W1h;
    const u16* __restrict__ Wl = phase ? W2l : W1l;
    for (int k0 = 0; k0 < K; k0 += 32) {
      __syncthreads();
      {
        size_t so = (size_t)(bm0 + srow) * K + k0 + sg * 8;
        GLOAD16(Ah + so, &sAh[t * 8]);
        GLOAD16(Al + so, &sAl[t * 8]);
      }
#pragma unroll
      for (int q = 0; q < 4; ++q) {
        size_t so = (size_t)t * K + k0 + q * 8;
        GLOAD16(Wh + so, &sBh[q * 2048 + t * 8]);
        GLOAD16(Wl + so, &sBl[q * 2048 + t * 8]);
      }
      __syncthreads();  // compiler drains vmcnt(0) before s_barrier

      s16x8 ah[4], al[4];
#pragma unroll
      for (int m = 0; m < 4; ++m) {
        int ao = (l >> 4) * 512 + (m * 16 + (l & 15)) * 8;
        ah[m] = *(const s16x8*)&sAh[ao];
        al[m] = *(const s16x8*)&sAl[ao];
      }
#pragma unroll
      for (int n = 0; n < 4; ++n) {
        int bo = (l >> 4) * 2048 + (w * 64 + n * 16 + (l & 15)) * 8;
        s16x8 bh = *(const s16x8*)&sBh[bo];
        s16x8 bl = *(const s16x8*)&sBl[bo];
#pragma unroll
        for (int m = 0; m < 4; ++m) {
          acc[m][n] = __builtin_amdgcn_mfma_f32_16x16x32_bf16(ah[m], bh, acc[m][n], 0, 0, 0);
          acc[m][n] = __builtin_amdgcn_mfma_f32_16x16x32_bf16(al[m], bh, acc[m][n], 0, 0, 0);
          acc[m][n] = __builtin_amdgcn_mfma_f32_16x16x32_bf16(ah[m], bl, acc[m][n], 0, 0, 0);
        }
      }
    }
  }

  // epilogue: D col = lane&15 (+16n+64w), row = (lane>>4)*4 + j (+16m)
  const int colb = w * 64 + (l & 15);
  const int rw = (l >> 4) * 4;
#pragma unroll
  for (int n = 0; n < 4; ++n) {
    int col = colb + n * 16;
    float bc = bias[col];
#pragma unroll
    for (int m = 0; m < 4; ++m) {
#pragma unroll
      for (int j = 0; j < 4; ++j) {
        int r = bm0 + m * 16 + rw + j;
        if (r < M) {
          float v = fmaxf(acc[m][n][j] + bc, 0.f);
          if (OUT_HL) {
            u16 h, lo2;
            split_hl(v, h, lo2);
            Ohi[(size_t)r * 256 + col] = h;
            Olo[(size_t)r * 256 + col] = lo2;
          } else {
            Of32[(size_t)r * 256 + col] = v;
          }
        }
      }
    }
  }
}

// ---------------------------------------------------------------------------
// Classifier: out[M][16] = h2[M][256] @ wc[256][16] + bc
// ---------------------------------------------------------------------------
__global__ void k_classifier(const float* __restrict__ h2, const float* __restrict__ wc,
                             const float* __restrict__ bc, float* __restrict__ outv, int M) {
  __shared__ float wcs[4096];
  __shared__ float bcs[16];
  const int t = threadIdx.x;
  for (int i = t; i < 4096; i += 256) wcs[i] = wc[i];
  if (t < 16) bcs[t] = bc[t];
  __syncthreads();
  int row = blockIdx.x * 16 + (t >> 4);
  int cls = t & 15;
  if (row >= M) return;
  const float* hr = h2 + (size_t)row * 256;
  float acc = 0.f;
  for (int k = 0; k < 256; k += 4) {
    float4 h = *(const float4*)&hr[k];
    acc += h.x * wcs[(k + 0) * 16 + cls];
    acc += h.y * wcs[(k + 1) * 16 + cls];
    acc += h.z * wcs[(k + 2) * 16 + cls];
    acc += h.w * wcs[(k + 3) * 16 + cls];
  }
  outv[(size_t)row * 16 + cls] = acc + bcs[cls];
}

// ---------------------------------------------------------------------------
extern "C" void kernel_launch(void* const* d_in, const int* in_sizes, int n_in,
                              void* d_out, int out_size, void* d_ws, size_t ws_size,
                              hipStream_t stream) {
  const float* x = (const float*)d_in[0];
  const int* ei = (const int*)d_in[1];
  const float* w1l = (const float*)d_in[2];
  const float* b1l = (const float*)d_in[3];
  const float* w1r = (const float*)d_in[4];
  const float* w2l = (const float*)d_in[5];
  const float* b2l = (const float*)d_in[6];
  const float* w2r = (const float*)d_in[7];
  const float* wc = (const float*)d_in[8];
  const float* bc = (const float*)d_in[9];
  float* outp = (float*)d_out;

  const int nE = in_sizes[1] / 2;        // 600000
  const int M = in_sizes[0] / 128;       // 50000
  const int Mpad = (M + 63) & ~63;       // 50048
  const int* src = ei;
  const int* dst = ei + nE;

  char* ws = (char*)d_ws;
  const size_t SZ_P128 = (size_t)Mpad * 128 * 2;  // 12812288
  const size_t SZ_P256 = (size_t)Mpad * 256 * 2;  // 25624576

  int* deg = (int*)(ws + 0);
  int* cursor = (int*)(ws + 262144);
  int* rowstart = (int*)(ws + 524288);
  int* partials = (int*)(ws + 786432);
  int* csr = (int*)(ws + 1048576);
  u16* wt1l_h = (u16*)(ws + 3670016);
  u16* wt1l_l = (u16*)(ws + 3735552);
  u16* wt1r_h = (u16*)(ws + 3801088);
  u16* wt1r_l = (u16*)(ws + 3866624);
  u16* wt2l_h = (u16*)(ws + 3932160);
  u16* wt2l_l = (u16*)(ws + 4063232);
  u16* wt2r_h = (u16*)(ws + 4194304);
  u16* wt2r_l = (u16*)(ws + 4325376);
  char* big = ws + 4718592;
  u16* x_hi = (u16*)(big);
  u16* x_lo = (u16*)(big + SZ_P128);
  u16* n1_hi = (u16*)(big + 2 * SZ_P128);
  u16* n1_lo = (u16*)(big + 3 * SZ_P128);
  float* h2 = (float*)(big);  // overlays x/n1 planes (disjoint lifetime)
  char* big2 = big + 4 * SZ_P128;
  u16* h1_hi = (u16*)(big2);
  u16* h1_lo = (u16*)(big2 + SZ_P256);
  u16* n2_hi = (u16*)(big2 + 2 * SZ_P256);
  u16* n2_lo = (u16*)(big2 + 3 * SZ_P256);

  hipMemsetAsync(deg, 0, (size_t)M * sizeof(int), stream);
  hipMemsetAsync(cursor, 0, (size_t)M * sizeof(int), stream);

  const int eb = (nE + 255) / 256;
  k_hist<<<eb, 256, 0, stream>>>(dst, deg, nE);
  const int nchunk = (M + 1023) / 1024;
  k_scan_chunks<<<nchunk, 256, 0, stream>>>(deg, rowstart, partials, M);
  k_scan_partials<<<1, 64, 0, stream>>>(partials, nchunk);
  k_add_offsets<<<(M + 1 + 255) / 256, 256, 0, stream>>>(rowstart, partials, M, nE);
  k_fill<<<eb, 256, 0, stream>>>(src, dst, rowstart, cursor, csr, nE);

  // converts
  long nx = (long)M * 128;
  k_cvt<<<(int)((nx / 4 + 255) / 256), 256, 0, stream>>>(x, x_hi, x_lo, nx);
  k_cvt_wt<<<(128 * 256 + 255) / 256, 256, 0, stream>>>(w1l, wt1l_h, wt1l_l, 128, 256);
  k_cvt_wt<<<(128 * 256 + 255) / 256, 256, 0, stream>>>(w1r, wt1r_h, wt1r_l, 128, 256);
  k_cvt_wt<<<(256 * 256 + 255) / 256, 256, 0, stream>>>(w2l, wt2l_h, wt2l_l, 256, 256);
  k_cvt_wt<<<(256 * 256 + 255) / 256, 256, 0, stream>>>(w2r, wt2r_h, wt2r_l, 256, 256);

  const int gemm_grid = (M + 63) / 64;

  // Layer 1
  k_agg128_hl<<<(M * 64 + 255) / 256, 256, 0, stream>>>(x, rowstart, csr, n1_hi, n1_lo, M);
  k_gemm_mfma<1><<<gemm_grid, 256, 0, stream>>>(n1_hi, n1_lo, x_hi, x_lo, wt1l_h, wt1l_l,
                                                wt1r_h, wt1r_l, b1l, h1_hi, h1_lo, nullptr,
                                                M, 128);
  // Layer 2
  k_agg256_hl<<<(M * 64 + 255) / 256, 256, 0, stream>>>(h1_hi, h1_lo, rowstart, csr, n2_hi,
                                                        n2_lo, M);
  k_gemm_mfma<0><<<gemm_grid, 256, 0, stream>>>(n2_hi, n2_lo, h1_hi, h1_lo, wt2l_h, wt2l_l,
                                                wt2r_h, wt2r_l, b2l, nullptr, nullptr, h2,
                                                M, 256);
  // Classifier
  k_classifier<<<(M + 15) / 16, 256, 0, stream>>>(h2, wc, bc, outp, M);
}

// Round 4
// 488.242 us; speedup vs baseline: 1.2436x; 1.1769x over previous
//
#include <hip/hip_runtime.h>
#include <hip/hip_bf16.h>

typedef unsigned short u16;
typedef __attribute__((ext_vector_type(8))) short s16x8;
typedef __attribute__((ext_vector_type(4))) float f32x4;

#define GLOAD16(src, dst)                                                   \
  __builtin_amdgcn_global_load_lds(                                         \
      (const __attribute__((address_space(1))) void*)(src),                 \
      (__attribute__((address_space(3))) void*)(dst), 16, 0, 0)

__device__ inline u16 f2bf(float f) {
  unsigned u = __float_as_uint(f);
  unsigned r = u + 0x7FFFu + ((u >> 16) & 1u);
  return (u16)(r >> 16);
}
__device__ inline float bf2f(u16 h) { return __uint_as_float(((unsigned)h) << 16); }
__device__ inline void split_hl(float f, u16& hi, u16& lo) {
  hi = f2bf(f);
  lo = f2bf(f - bf2f(hi));
}

// ---------------------------------------------------------------------------
// CSR build
// ---------------------------------------------------------------------------
__global__ void k_hist(const int* __restrict__ dst, int* __restrict__ deg, int nE) {
  int i = blockIdx.x * blockDim.x + threadIdx.x;
  if (i < nE) atomicAdd(&deg[dst[i]], 1);
}

__global__ void k_scan_chunks(const int* __restrict__ deg, int* __restrict__ excl,
                              int* __restrict__ partials, int n) {
  __shared__ int sd[256];
  const int t = threadIdx.x;
  const int base = blockIdx.x * 1024 + t * 4;
  int v0 = (base + 0 < n) ? deg[base + 0] : 0;
  int v1 = (base + 1 < n) ? deg[base + 1] : 0;
  int v2 = (base + 2 < n) ? deg[base + 2] : 0;
  int v3 = (base + 3 < n) ? deg[base + 3] : 0;
  sd[t] = v0 + v1 + v2 + v3;
  __syncthreads();
  for (int off = 1; off < 256; off <<= 1) {
    int x = 0;
    if (t >= off) x = sd[t - off];
    __syncthreads();
    sd[t] += x;
    __syncthreads();
  }
  int run = (t > 0) ? sd[t - 1] : 0;
  if (base + 0 < n) excl[base + 0] = run;
  run += v0;
  if (base + 1 < n) excl[base + 1] = run;
  run += v1;
  if (base + 2 < n) excl[base + 2] = run;
  run += v2;
  if (base + 3 < n) excl[base + 3] = run;
  if (t == 255) partials[blockIdx.x] = sd[255];
}

__global__ void k_scan_partials(int* __restrict__ partials, int nchunk) {
  const int t = threadIdx.x;
  int orig = (t < nchunk) ? partials[t] : 0;
  int v = orig;
  for (int off = 1; off < 64; off <<= 1) {
    int y = __shfl_up(v, off, 64);
    if (t >= off) v += y;
  }
  if (t < nchunk) partials[t] = v - orig;
}

__global__ void k_add_offsets(int* __restrict__ rowstart, const int* __restrict__ chunk_off,
                              int n, int nE) {
  int i = blockIdx.x * blockDim.x + threadIdx.x;
  if (i < n) rowstart[i] += chunk_off[i >> 10];
  if (i == n) rowstart[n] = nE;
}

__global__ void k_fill(const int* __restrict__ src, const int* __restrict__ dst,
                       const int* __restrict__ rowstart, int* __restrict__ cursor,
                       int* __restrict__ csr, int nE) {
  int i = blockIdx.x * blockDim.x + threadIdx.x;
  if (i < nE) {
    int d = dst[i];
    int p = rowstart[d] + atomicAdd(&cursor[d], 1);
    csr[p] = src[i];
  }
}

// ---------------------------------------------------------------------------
// fp32 -> bf16 hi/lo plane converters
// ---------------------------------------------------------------------------
__global__ void k_cvt(const float* __restrict__ X, u16* __restrict__ hi,
                      u16* __restrict__ lo, long n) {
  long i = (long)(blockIdx.x * blockDim.x + threadIdx.x) * 4;
  if (i >= n) return;
  float4 v = *(const float4*)&X[i];
  u16 h0, l0, h1, l1, h2, l2, h3, l3;
  split_hl(v.x, h0, l0);
  split_hl(v.y, h1, l1);
  split_hl(v.z, h2, l2);
  split_hl(v.w, h3, l3);
  *(ushort4*)&hi[i] = make_ushort4(h0, h1, h2, h3);
  *(ushort4*)&lo[i] = make_ushort4(l0, l1, l2, l3);
}

// W[K][N] -> WT_hi/lo[N][K]
__global__ void k_cvt_wt(const float* __restrict__ W, u16* __restrict__ thi,
                         u16* __restrict__ tlo, int K, int N) {
  int i = blockIdx.x * blockDim.x + threadIdx.x;
  if (i >= K * N) return;
  int k = i / N, n = i - k * N;
  u16 h, l;
  split_hl(W[i], h, l);
  thi[n * K + k] = h;
  tlo[n * K + k] = l;
}

// ---------------------------------------------------------------------------
// Mean aggregation (one wave per node), hi/lo bf16 outputs
// ---------------------------------------------------------------------------
__global__ void k_agg128_hl(const float* __restrict__ X, const int* __restrict__ rs,
                            const int* __restrict__ csr, u16* __restrict__ ohi,
                            u16* __restrict__ olo, int M) {
  int wid = (blockIdx.x * blockDim.x + threadIdx.x) >> 6;
  int lane = threadIdx.x & 63;
  if (wid >= M) return;
  int s0 = rs[wid], s1 = rs[wid + 1];
  float ax = 0.f, ay = 0.f;
  int e = s0;
  for (; e + 1 < s1; e += 2) {
    int sa = csr[e], sb = csr[e + 1];
    float2 va = *(const float2*)&X[(size_t)sa * 128 + lane * 2];
    float2 vb = *(const float2*)&X[(size_t)sb * 128 + lane * 2];
    ax += va.x + vb.x;
    ay += va.y + vb.y;
  }
  if (e < s1) {
    float2 va = *(const float2*)&X[(size_t)csr[e] * 128 + lane * 2];
    ax += va.x;
    ay += va.y;
  }
  float inv = 1.0f / fmaxf((float)(s1 - s0), 1.0f);
  ax *= inv;
  ay *= inv;
  u16 h0, l0, h1, l1;
  split_hl(ax, h0, l0);
  split_hl(ay, h1, l1);
  size_t o = (size_t)wid * 128 + lane * 2;
  *(ushort2*)&ohi[o] = make_ushort2(h0, h1);
  *(ushort2*)&olo[o] = make_ushort2(l0, l1);
}

__global__ void k_agg256_hl(const u16* __restrict__ Xhi, const u16* __restrict__ Xlo,
                            const int* __restrict__ rs, const int* __restrict__ csr,
                            u16* __restrict__ ohi, u16* __restrict__ olo, int M) {
  int wid = (blockIdx.x * blockDim.x + threadIdx.x) >> 6;
  int lane = threadIdx.x & 63;
  if (wid >= M) return;
  int s0 = rs[wid], s1 = rs[wid + 1];
  float a0 = 0.f, a1 = 0.f, a2 = 0.f, a3 = 0.f;
  int e = s0;
  for (; e + 1 < s1; e += 2) {
    size_t ba = (size_t)csr[e] * 256 + lane * 4;
    size_t bb = (size_t)csr[e + 1] * 256 + lane * 4;
    ushort4 ha = *(const ushort4*)&Xhi[ba];
    ushort4 la = *(const ushort4*)&Xlo[ba];
    ushort4 hb = *(const ushort4*)&Xhi[bb];
    ushort4 lb = *(const ushort4*)&Xlo[bb];
    a0 += bf2f(ha.x) + bf2f(la.x) + bf2f(hb.x) + bf2f(lb.x);
    a1 += bf2f(ha.y) + bf2f(la.y) + bf2f(hb.y) + bf2f(lb.y);
    a2 += bf2f(ha.z) + bf2f(la.z) + bf2f(hb.z) + bf2f(lb.z);
    a3 += bf2f(ha.w) + bf2f(la.w) + bf2f(hb.w) + bf2f(lb.w);
  }
  if (e < s1) {
    size_t ba = (size_t)csr[e] * 256 + lane * 4;
    ushort4 ha = *(const ushort4*)&Xhi[ba];
    ushort4 la = *(const ushort4*)&Xlo[ba];
    a0 += bf2f(ha.x) + bf2f(la.x);
    a1 += bf2f(ha.y) + bf2f(la.y);
    a2 += bf2f(ha.z) + bf2f(la.z);
    a3 += bf2f(ha.w) + bf2f(la.w);
  }
  float inv = 1.0f / fmaxf((float)(s1 - s0), 1.0f);
  a0 *= inv;
  a1 *= inv;
  a2 *= inv;
  a3 *= inv;
  u16 h0, l0, h1, l1, h2, l2, h3, l3;
  split_hl(a0, h0, l0);
  split_hl(a1, h1, l1);
  split_hl(a2, h2, l2);
  split_hl(a3, h3, l3);
  size_t o = (size_t)wid * 256 + lane * 4;
  *(ushort4*)&ohi[o] = make_ushort4(h0, h1, h2, h3);
  *(ushort4*)&olo[o] = make_ushort4(l0, l1, l2, l3);
}

// ---------------------------------------------------------------------------
// Dual bf16x3 MFMA GEMM, 2-phase pipelined (T3 minimum template):
// C[M][bn0:bn0+128] = relu(A1@W1 + A2@W2 + bias)
// BM=128, BN=128, BK=32, double-buffered LDS, 4 waves (2x2), 64x64 out/wave.
// Per K-step per thread: 8 x global_load_lds(16B) staged for NEXT step while
// computing current; single __syncthreads (vmcnt drain) per step.
// ---------------------------------------------------------------------------
template <int OUT_HL>
__global__ __launch_bounds__(256) void k_gemm_mfma(
    const u16* __restrict__ A1h, const u16* __restrict__ A1l,
    const u16* __restrict__ A2h, const u16* __restrict__ A2l,
    const u16* __restrict__ W1h, const u16* __restrict__ W1l,
    const u16* __restrict__ W2h, const u16* __restrict__ W2l,
    const float* __restrict__ bias, u16* __restrict__ Ohi, u16* __restrict__ Olo,
    float* __restrict__ Of32, int M, int K) {
  // per buf, per plane: [4 kgrp][128 row][8 shorts] = 8 KB; total 64 KB
  __shared__ short sAh[2][4096], sAl[2][4096], sBh[2][4096], sBl[2][4096];
  const int t = threadIdx.x;
  const int l = t & 63;
  const int w = t >> 6;
  const int wr = w >> 1, wc = w & 1;
  const int bm0 = blockIdx.x * 128;
  const int bn0 = blockIdx.y * 128;
  const int NT = (2 * K) / 32;

  f32x4 acc[4][4];
#pragma unroll
  for (int m = 0; m < 4; m++)
#pragma unroll
    for (int n = 0; n < 4; n++) acc[m][n] = (f32x4){0.f, 0.f, 0.f, 0.f};

  // staging decode: slot = q*256 + t; kgrp = slot>>7, row = slot&127
  const int s0 = t, s1 = 256 + t;
  const int kg0 = s0 >> 7, r0 = s0 & 127;
  const int kg1 = s1 >> 7, r1 = s1 & 127;

#define STAGE(buf, it)                                                        \
  do {                                                                        \
    int kk_ = (it) * 32;                                                      \
    int ph_ = kk_ >= K;                                                       \
    int kb_ = kk_ - (ph_ ? K : 0);                                            \
    const u16* Ah_ = ph_ ? A2h : A1h;                                         \
    const u16* Al_ = ph_ ? A2l : A1l;                                         \
    const u16* Bh_ = ph_ ? W2h : W1h;                                         \
    const u16* Bl_ = ph_ ? W2l : W1l;                                         \
    size_t a0_ = (size_t)(bm0 + r0) * K + kb_ + kg0 * 8;                      \
    size_t a1_ = (size_t)(bm0 + r1) * K + kb_ + kg1 * 8;                      \
    size_t b0_ = (size_t)(bn0 + r0) * K + kb_ + kg0 * 8;                      \
    size_t b1_ = (size_t)(bn0 + r1) * K + kb_ + kg1 * 8;                      \
    GLOAD16(Ah_ + a0_, &sAh[buf][s0 * 8]);                                    \
    GLOAD16(Ah_ + a1_, &sAh[buf][s1 * 8]);                                    \
    GLOAD16(Al_ + a0_, &sAl[buf][s0 * 8]);                                    \
    GLOAD16(Al_ + a1_, &sAl[buf][s1 * 8]);                                    \
    GLOAD16(Bh_ + b0_, &sBh[buf][s0 * 8]);                                    \
    GLOAD16(Bh_ + b1_, &sBh[buf][s1 * 8]);                                    \
    GLOAD16(Bl_ + b0_, &sBl[buf][s0 * 8]);                                    \
    GLOAD16(Bl_ + b1_, &sBl[buf][s1 * 8]);                                    \
  } while (0)

  STAGE(0, 0);
  __syncthreads();

  const int kg = l >> 4;
  const int lr = l & 15;
  for (int it = 0; it < NT; ++it) {
    const int buf = it & 1;
    if (it + 1 < NT) STAGE(buf ^ 1, it + 1);

    s16x8 ah[4], al[4];
#pragma unroll
    for (int m = 0; m < 4; ++m) {
      int ao = kg * 1024 + (wr * 64 + m * 16 + lr) * 8;
      ah[m] = *(const s16x8*)&sAh[buf][ao];
      al[m] = *(const s16x8*)&sAl[buf][ao];
    }
#pragma unroll
    for (int n = 0; n < 4; ++n) {
      int bo = kg * 1024 + (wc * 64 + n * 16 + lr) * 8;
      s16x8 bh = *(const s16x8*)&sBh[buf][bo];
      s16x8 bl = *(const s16x8*)&sBl[buf][bo];
#pragma unroll
      for (int m = 0; m < 4; ++m) {
        acc[m][n] = __builtin_amdgcn_mfma_f32_16x16x32_bf16(ah[m], bh, acc[m][n], 0, 0, 0);
        acc[m][n] = __builtin_amdgcn_mfma_f32_16x16x32_bf16(al[m], bh, acc[m][n], 0, 0, 0);
        acc[m][n] = __builtin_amdgcn_mfma_f32_16x16x32_bf16(ah[m], bl, acc[m][n], 0, 0, 0);
      }
    }
    __syncthreads();
  }
#undef STAGE

  // epilogue: D col = lane&15 (+16n), row = (lane>>4)*4 + j (+16m)
  const int colb = bn0 + wc * 64 + lr;
  const int rwb = bm0 + wr * 64 + (l >> 4) * 4;
#pragma unroll
  for (int n = 0; n < 4; ++n) {
    int col = colb + n * 16;
    float bc = bias[col];
#pragma unroll
    for (int m = 0; m < 4; ++m) {
#pragma unroll
      for (int j = 0; j < 4; ++j) {
        int r = rwb + m * 16 + j;
        if (r < M) {
          float v = fmaxf(acc[m][n][j] + bc, 0.f);
          if (OUT_HL) {
            u16 h, lo2;
            split_hl(v, h, lo2);
            Ohi[(size_t)r * 256 + col] = h;
            Olo[(size_t)r * 256 + col] = lo2;
          } else {
            Of32[(size_t)r * 256 + col] = v;
          }
        }
      }
    }
  }
}

// ---------------------------------------------------------------------------
// Classifier: out[M][16] = h2[M][256] @ wc[256][16] + bc
// ---------------------------------------------------------------------------
__global__ void k_classifier(const float* __restrict__ h2, const float* __restrict__ wc,
                             const float* __restrict__ bc, float* __restrict__ outv, int M) {
  __shared__ float wcs[4096];
  __shared__ float bcs[16];
  const int t = threadIdx.x;
  for (int i = t; i < 4096; i += 256) wcs[i] = wc[i];
  if (t < 16) bcs[t] = bc[t];
  __syncthreads();
  int row = blockIdx.x * 16 + (t >> 4);
  int cls = t & 15;
  if (row >= M) return;
  const float* hr = h2 + (size_t)row * 256;
  float acc = 0.f;
  for (int k = 0; k < 256; k += 4) {
    float4 h = *(const float4*)&hr[k];
    acc += h.x * wcs[(k + 0) * 16 + cls];
    acc += h.y * wcs[(k + 1) * 16 + cls];
    acc += h.z * wcs[(k + 2) * 16 + cls];
    acc += h.w * wcs[(k + 3) * 16 + cls];
  }
  outv[(size_t)row * 16 + cls] = acc + bcs[cls];
}

// ---------------------------------------------------------------------------
extern "C" void kernel_launch(void* const* d_in, const int* in_sizes, int n_in,
                              void* d_out, int out_size, void* d_ws, size_t ws_size,
                              hipStream_t stream) {
  const float* x = (const float*)d_in[0];
  const int* ei = (const int*)d_in[1];
  const float* w1l = (const float*)d_in[2];
  const float* b1l = (const float*)d_in[3];
  const float* w1r = (const float*)d_in[4];
  const float* w2l = (const float*)d_in[5];
  const float* b2l = (const float*)d_in[6];
  const float* w2r = (const float*)d_in[7];
  const float* wc = (const float*)d_in[8];
  const float* bc = (const float*)d_in[9];
  float* outp = (float*)d_out;

  const int nE = in_sizes[1] / 2;        // 600000
  const int M = in_sizes[0] / 128;       // 50000
  const int Mpad = (M + 127) & ~127;     // 50048
  const int* src = ei;
  const int* dst = ei + nE;

  char* ws = (char*)d_ws;
  const size_t SZ_P128 = (size_t)Mpad * 128 * 2;
  const size_t SZ_P256 = (size_t)Mpad * 256 * 2;

  int* deg = (int*)(ws + 0);
  int* cursor = (int*)(ws + 262144);
  int* rowstart = (int*)(ws + 524288);
  int* partials = (int*)(ws + 786432);
  int* csr = (int*)(ws + 1048576);
  u16* wt1l_h = (u16*)(ws + 3670016);
  u16* wt1l_l = (u16*)(ws + 3735552);
  u16* wt1r_h = (u16*)(ws + 3801088);
  u16* wt1r_l = (u16*)(ws + 3866624);
  u16* wt2l_h = (u16*)(ws + 3932160);
  u16* wt2l_l = (u16*)(ws + 4063232);
  u16* wt2r_h = (u16*)(ws + 4194304);
  u16* wt2r_l = (u16*)(ws + 4325376);
  char* big = ws + 4718592;
  u16* x_hi = (u16*)(big);
  u16* x_lo = (u16*)(big + SZ_P128);
  u16* n1_hi = (u16*)(big + 2 * SZ_P128);
  u16* n1_lo = (u16*)(big + 3 * SZ_P128);
  float* h2 = (float*)(big);  // overlays x/n1 planes (disjoint lifetime)
  char* big2 = big + 4 * SZ_P128;
  u16* h1_hi = (u16*)(big2);
  u16* h1_lo = (u16*)(big2 + SZ_P256);
  u16* n2_hi = (u16*)(big2 + 2 * SZ_P256);
  u16* n2_lo = (u16*)(big2 + 3 * SZ_P256);

  hipMemsetAsync(deg, 0, (size_t)M * sizeof(int), stream);
  hipMemsetAsync(cursor, 0, (size_t)M * sizeof(int), stream);

  const int eb = (nE + 255) / 256;
  k_hist<<<eb, 256, 0, stream>>>(dst, deg, nE);
  const int nchunk = (M + 1023) / 1024;
  k_scan_chunks<<<nchunk, 256, 0, stream>>>(deg, rowstart, partials, M);
  k_scan_partials<<<1, 64, 0, stream>>>(partials, nchunk);
  k_add_offsets<<<(M + 1 + 255) / 256, 256, 0, stream>>>(rowstart, partials, M, nE);
  k_fill<<<eb, 256, 0, stream>>>(src, dst, rowstart, cursor, csr, nE);

  // converts
  long nx = (long)M * 128;
  k_cvt<<<(int)((nx / 4 + 255) / 256), 256, 0, stream>>>(x, x_hi, x_lo, nx);
  k_cvt_wt<<<(128 * 256 + 255) / 256, 256, 0, stream>>>(w1l, wt1l_h, wt1l_l, 128, 256);
  k_cvt_wt<<<(128 * 256 + 255) / 256, 256, 0, stream>>>(w1r, wt1r_h, wt1r_l, 128, 256);
  k_cvt_wt<<<(256 * 256 + 255) / 256, 256, 0, stream>>>(w2l, wt2l_h, wt2l_l, 256, 256);
  k_cvt_wt<<<(256 * 256 + 255) / 256, 256, 0, stream>>>(w2r, wt2r_h, wt2r_l, 256, 256);

  dim3 ggrid(Mpad / 128, 2);

  // Layer 1
  k_agg128_hl<<<(M * 64 + 255) / 256, 256, 0, stream>>>(x, rowstart, csr, n1_hi, n1_lo, M);
  k_gemm_mfma<1><<<ggrid, 256, 0, stream>>>(n1_hi, n1_lo, x_hi, x_lo, wt1l_h, wt1l_l,
                                            wt1r_h, wt1r_l, b1l, h1_hi, h1_lo, nullptr,
                                            M, 128);
  // Layer 2
  k_agg256_hl<<<(M * 64 + 255) / 256, 256, 0, stream>>>(h1_hi, h1_lo, rowstart, csr, n2_hi,
                                                        n2_lo, M);
  k_gemm_mfma<0><<<ggrid, 256, 0, stream>>>(n2_hi, n2_lo, h1_hi, h1_lo, wt2l_h, wt2l_l,
                                            wt2r_h, wt2r_l, b2l, nullptr, nullptr, h2,
                                            M, 256);
  // Classifier
  k_classifier<<<(M + 15) / 16, 256, 0, stream>>>(h2, wc, bc, outp, M);
}